// Round 2
// baseline (10529.501 us; speedup 1.0000x reference)
//
#include <hip/hip_runtime.h>

#define S   512
#define B   256
#define D   128
#define H1  128
#define G1  512
#define H2  256
#define G2  1024

#define NA_U 4
#define NA_B 8
#define NWG_A 32
#define NB_U 16
#define NB_B 8
#define NWG_B 128
#define NWG 160

// ws layout (float offsets)
#define WS_XPROJ 0                    // [B][G1] = 131072
#define WS_HP1   131072               // [2][B][H1] = 65536
#define WS_HP2   196608               // [2][B][H2] = 131072
#define WS_OUTP  327680               // [S][NB_U][B] = 2097152
#define WS_BAR   2424832              // int region from here (8192 ints)

#define DYN_LDS 148224                // bytes (B-group partition is the max)

__device__ __forceinline__ float sigm(float x){ return 1.f/(1.f+__expf(-x)); }
__device__ __forceinline__ float tanhx(float x){
  x = fminf(fmaxf(x, -30.f), 30.f);
  float e = __expf(-2.f*x);
  return (1.f - e)/(1.f + e);
}

// ---------------- init kernels ----------------
__global__ void k_zero(float* ws){
  long long id = (long long)blockIdx.x*blockDim.x + threadIdx.x;
  long long stride = (long long)gridDim.x*blockDim.x;
  for (long long i = id; i < 196608; i += stride) ws[WS_HP1 + i] = 0.f; // hp1 + hp2
  int* bar = (int*)(ws + WS_BAR);
  for (long long i = id; i < 8192; i += stride) bar[i] = 0;
}

__global__ void k_xproj(const float* __restrict__ x, const float* __restrict__ Wih1,
                        const float* __restrict__ bih1, const float* __restrict__ bhh1,
                        float* __restrict__ ws){
  __shared__ float xs[D];
  int b = blockIdx.x;
  for (int d = threadIdx.x; d < D; d += blockDim.x) xs[d] = x[b*D + d];
  __syncthreads();
  for (int g = threadIdx.x; g < G1; g += blockDim.x){
    float acc = bih1[g] + bhh1[g];
    const float* w = &Wih1[(size_t)g*D];
    #pragma unroll 8
    for (int d = 0; d < D; ++d) acc += xs[d]*w[d];
    ws[WS_XPROJ + (size_t)b*G1 + g] = acc;
  }
}

// ---------------- grid barrier ----------------
__device__ __forceinline__ void gbar(int* arrive, int* release_, int wg, int t, int r){
  __syncthreads();
  if (t == 0){
    __builtin_amdgcn_fence(__ATOMIC_RELEASE, "agent");
    __hip_atomic_store(&arrive[wg*32], r+1, __ATOMIC_RELAXED, __HIP_MEMORY_SCOPE_AGENT);
  }
  if (wg == 0){
    if (t < NWG){
      while (__hip_atomic_load(&arrive[t*32], __ATOMIC_RELAXED, __HIP_MEMORY_SCOPE_AGENT) < r+1){
        __builtin_amdgcn_s_sleep(1);
      }
    }
    __syncthreads();
    if (t == 0){
      __builtin_amdgcn_fence(__ATOMIC_SEQ_CST, "agent");
      __hip_atomic_store(release_, r+1, __ATOMIC_RELAXED, __HIP_MEMORY_SCOPE_AGENT);
    }
  } else {
    if (t == 0){
      while (__hip_atomic_load(release_, __ATOMIC_RELAXED, __HIP_MEMORY_SCOPE_AGENT) < r+1){
        __builtin_amdgcn_s_sleep(1);
      }
    }
  }
  __syncthreads();
  __builtin_amdgcn_fence(__ATOMIC_ACQUIRE, "agent");
}

// ---------------- persistent LSTM kernel ----------------
__global__ void __launch_bounds__(256, 1)
k_persist(const float* __restrict__ Whh1,
          const float* __restrict__ Wih2, const float* __restrict__ Whh2,
          const float* __restrict__ bih2, const float* __restrict__ bhh2,
          const float* __restrict__ Wout,
          float* __restrict__ ws){
  extern __shared__ float sm[];
  const int wg = blockIdx.x;
  const int t  = threadIdx.x;
  float* hp1  = ws + WS_HP1;   // [2][B][H1]
  float* hp2  = ws + WS_HP2;   // [2][B][H2]
  float* outp = ws + WS_OUTP;  // [S][NB_U][B]
  int* arrive   = (int*)(ws + WS_BAR);
  int* release_ = arrive + NWG*32;

  if (wg < NWG_A){
    // ======= layer-1 group: units 32/WG, batch 32/WG =======
    float* wt1 = sm;               // [128 k][128 lg]
    float* ha  = sm + 16384;       // [32][132]
    float* xp  = ha + 32*132;      // [32][128]
    const int us = wg % NA_U, bs = wg / NA_U;
    const int u0 = us*32, b0 = bs*32;
    const int tx = t & 31, ty = t >> 5, bb = ty*4;
    // stage W_hh1 slice (once), k-major; lg = lu*4 + gate
    for (int j = t; j < 128*128; j += 256){
      int k = j & 127, lg = j >> 7;
      int lu = lg >> 2, gi = lg & 3;
      wt1[k*128 + lg] = Whh1[(size_t)(gi*H1 + u0 + lu)*D + k];
    }
    // stage xproj slice (once), local-gate layout
    for (int j = t; j < 32*128; j += 256){
      int lg = j & 127, bl = j >> 7;
      int lu = lg >> 2, gi = lg & 3;
      xp[bl*128 + lg] = ws[WS_XPROJ + (size_t)(b0 + bl)*G1 + gi*H1 + u0 + lu];
    }
    float c1r[4] = {0.f,0.f,0.f,0.f};
    __syncthreads();
    for (int r = 0; r <= S; ++r){
      if (r < S){
        const int pr = (r+1)&1, pw = r&1;
        const float4* hsrc = (const float4*)(hp1 + (size_t)pr*B*H1);
        for (int j = t; j < 1024; j += 256){
          int bl = j >> 5, k4 = j & 31;
          *(float4*)&ha[bl*132 + k4*4] = hsrc[(size_t)(b0+bl)*32 + k4];
        }
        __syncthreads();
        float acc[4][4];
        #pragma unroll
        for (int i=0;i<4;++i){
          #pragma unroll
          for (int j=0;j<4;++j) acc[i][j] = xp[(bb+i)*128 + tx*4 + j];
        }
        const float4* wv = (const float4*)wt1;
        for (int k = 0; k < 128; k += 4){
          float4 w0 = wv[(k+0)*32 + tx];
          float4 w1 = wv[(k+1)*32 + tx];
          float4 w2 = wv[(k+2)*32 + tx];
          float4 w3 = wv[(k+3)*32 + tx];
          #pragma unroll
          for (int i=0;i<4;++i){
            float4 h4 = *(const float4*)&ha[(bb+i)*132 + k];
            acc[i][0] += h4.x*w0.x; acc[i][1] += h4.x*w0.y; acc[i][2] += h4.x*w0.z; acc[i][3] += h4.x*w0.w;
            acc[i][0] += h4.y*w1.x; acc[i][1] += h4.y*w1.y; acc[i][2] += h4.y*w1.z; acc[i][3] += h4.y*w1.w;
            acc[i][0] += h4.z*w2.x; acc[i][1] += h4.z*w2.y; acc[i][2] += h4.z*w2.z; acc[i][3] += h4.z*w2.w;
            acc[i][0] += h4.w*w3.x; acc[i][1] += h4.w*w3.y; acc[i][2] += h4.w*w3.z; acc[i][3] += h4.w*w3.w;
          }
        }
        #pragma unroll
        for (int i=0;i<4;++i){
          float ig = sigm(acc[i][0]);
          float fg = sigm(acc[i][1]);
          float gg = tanhx(acc[i][2]);
          float og = sigm(acc[i][3]);
          c1r[i] = fg*c1r[i] + ig*gg;
          float h = og*tanhx(c1r[i]);
          hp1[(size_t)pw*B*H1 + (size_t)(b0+bb+i)*H1 + u0 + tx] = h;
        }
      }
      gbar(arrive, release_, wg, t, r);
    }
  } else {
    // ======= layer-2 group: units 16/WG, batch 32/WG =======
    float* wt2  = sm;              // [384 k][64 lg]
    float* hc   = sm + 384*64;     // [32][388]  (k<128: h1, k>=128: h2)
    float* bias = hc + 32*388;     // [64]
    const int wb = wg - NWG_A;
    const int us = wb % NB_U, bs = wb / NB_U;
    const int u0 = us*16, b0 = bs*32;
    const int tx = t & 15, ty = t >> 4, bb = ty*2;
    for (int j = t; j < 64*128; j += 256){
      int k = j & 127, lg = j >> 7;
      int lu = lg >> 2, gi = lg & 3;
      wt2[k*64 + lg] = Wih2[(size_t)(gi*H2 + u0 + lu)*D + k];
    }
    for (int j = t; j < 64*256; j += 256){
      int k = j & 255, lg = j >> 8;
      int lu = lg >> 2, gi = lg & 3;
      wt2[(128+k)*64 + lg] = Whh2[(size_t)(gi*H2 + u0 + lu)*H2 + k];
    }
    if (t < 64){
      int lu = t >> 2, gi = t & 3;
      bias[t] = bih2[gi*H2 + u0 + lu] + bhh2[gi*H2 + u0 + lu];
    }
    const float wout = Wout[u0 + tx];
    float c2r[2] = {0.f, 0.f};
    __syncthreads();
    for (int r = 0; r <= S; ++r){
      if (r >= 1){
        const int tstep = r - 1;
        const int p1 = (r-1)&1;
        const int p2r = r&1, p2w = (r-1)&1;
        const float4* h1s = (const float4*)(hp1 + (size_t)p1*B*H1);
        const float4* h2s = (const float4*)(hp2 + (size_t)p2r*B*H2);
        for (int j = t; j < 1024; j += 256){
          int bl = j >> 5, k4 = j & 31;
          *(float4*)&hc[bl*388 + k4*4] = h1s[(size_t)(b0+bl)*32 + k4];
        }
        for (int j = t; j < 2048; j += 256){
          int bl = j >> 6, k4 = j & 63;
          *(float4*)&hc[bl*388 + 128 + k4*4] = h2s[(size_t)(b0+bl)*64 + k4];
        }
        __syncthreads();
        float acc[2][4];
        #pragma unroll
        for (int i=0;i<2;++i){
          #pragma unroll
          for (int j=0;j<4;++j) acc[i][j] = bias[tx*4 + j];
        }
        const float4* wv = (const float4*)wt2;
        for (int k = 0; k < 384; k += 4){
          float4 w0 = wv[(k+0)*16 + tx];
          float4 w1 = wv[(k+1)*16 + tx];
          float4 w2 = wv[(k+2)*16 + tx];
          float4 w3 = wv[(k+3)*16 + tx];
          #pragma unroll
          for (int i=0;i<2;++i){
            float4 h4 = *(const float4*)&hc[(bb+i)*388 + k];
            acc[i][0] += h4.x*w0.x; acc[i][1] += h4.x*w0.y; acc[i][2] += h4.x*w0.z; acc[i][3] += h4.x*w0.w;
            acc[i][0] += h4.y*w1.x; acc[i][1] += h4.y*w1.y; acc[i][2] += h4.y*w1.z; acc[i][3] += h4.y*w1.w;
            acc[i][0] += h4.z*w2.x; acc[i][1] += h4.z*w2.y; acc[i][2] += h4.z*w2.z; acc[i][3] += h4.z*w2.w;
            acc[i][0] += h4.w*w3.x; acc[i][1] += h4.w*w3.y; acc[i][2] += h4.w*w3.z; acc[i][3] += h4.w*w3.w;
          }
        }
        float psum[2];
        #pragma unroll
        for (int i=0;i<2;++i){
          float ig = sigm(acc[i][0]);
          float fg = sigm(acc[i][1]);
          float gg = tanhx(acc[i][2]);
          float og = sigm(acc[i][3]);
          c2r[i] = fg*c2r[i] + ig*gg;
          float h = og*tanhx(c2r[i]);
          hp2[(size_t)p2w*B*H2 + (size_t)(b0+bb+i)*H2 + u0 + tx] = h;
          psum[i] = h*wout;
        }
        #pragma unroll
        for (int m = 1; m < 16; m <<= 1){
          psum[0] += __shfl_xor(psum[0], m, 64);
          psum[1] += __shfl_xor(psum[1], m, 64);
        }
        if (tx == 0){
          outp[(size_t)tstep*(NB_U*B) + us*B + (b0+bb)]     = psum[0];
          outp[(size_t)tstep*(NB_U*B) + us*B + (b0+bb+1)]   = psum[1];
        }
      }
      gbar(arrive, release_, wg, t, r);
    }
  }
}

// ---------------- final output assembly ----------------
__global__ void k_final(const float* __restrict__ ws, const float* __restrict__ bout,
                        float* __restrict__ out){
  int id = blockIdx.x*blockDim.x + threadIdx.x;
  if (id >= B*S) return;
  int tt = id >> 8;       // timestep
  int b  = id & 255;      // batch (consecutive lanes -> coalesced reads)
  float s = bout[0];
  const float* p = ws + WS_OUTP + (size_t)tt*(NB_U*B) + b;
  #pragma unroll
  for (int u = 0; u < NB_U; ++u) s += p[(size_t)u*B];
  out[(size_t)b*S + tt] = s;
}

extern "C" void kernel_launch(void* const* d_in, const int* in_sizes, int n_in,
                              void* d_out, int out_size, void* d_ws, size_t ws_size,
                              hipStream_t stream){
  const float* x    = (const float*)d_in[0];
  const float* Wih1 = (const float*)d_in[1];
  const float* Whh1 = (const float*)d_in[2];
  const float* bih1 = (const float*)d_in[3];
  const float* bhh1 = (const float*)d_in[4];
  const float* Wih2 = (const float*)d_in[5];
  const float* Whh2 = (const float*)d_in[6];
  const float* bih2 = (const float*)d_in[7];
  const float* bhh2 = (const float*)d_in[8];
  const float* Wout = (const float*)d_in[9];
  const float* bout = (const float*)d_in[10];
  float* ws  = (float*)d_ws;
  float* out = (float*)d_out;

  (void)hipFuncSetAttribute((const void*)k_persist,
                            hipFuncAttributeMaxDynamicSharedMemorySize, DYN_LDS);

  k_zero<<<dim3(64), dim3(256), 0, stream>>>(ws);
  k_xproj<<<dim3(B), dim3(256), 0, stream>>>(x, Wih1, bih1, bhh1, ws);
  k_persist<<<dim3(NWG), dim3(256), DYN_LDS, stream>>>(Whh1, Wih2, Whh2, bih2, bhh2, Wout, ws);
  k_final<<<dim3((B*S)/256), dim3(256), 0, stream>>>(ws, bout, out);
}

// Round 3
// 8372.075 us; speedup vs baseline: 1.2577x; 1.2577x over previous
//
#include <hip/hip_runtime.h>

#define S   512
#define B   256
#define D   128
#define H1  128
#define G1  512
#define H2  256
#define G2  1024

#define NA_U 4
#define NA_B 8
#define NWG_A 32
#define NB_U 16
#define NB_B 8
#define NWG_B 128
#define NWG 160
#define GRP_SZ 20               // 4 L1 + 16 L2 WGs per batch-slice group

// ws layout (float offsets)
#define WS_XPROJ 0                    // [B][G1] = 131072
#define WS_HP1   131072               // [2][B][H1] = 65536
#define WS_HP2   196608               // [2][B][H2] = 131072
#define WS_OUTP  327680               // [S][NB_U][B] = 2097152
#define WS_BAR   2424832              // int region from here (8192 ints)

#define DYN_LDS 148224                // bytes (B-group partition is the max)

typedef unsigned long long ull;

__device__ __forceinline__ float sigm(float x){ return 1.f/(1.f+__expf(-x)); }
__device__ __forceinline__ float tanhx(float x){
  x = fminf(fmaxf(x, -30.f), 30.f);
  float e = __expf(-2.f*x);
  return (1.f - e)/(1.f + e);
}

// coherent (L2-bypassing) accessors for cross-WG data
__device__ __forceinline__ void astf(float* p, float v){
  __hip_atomic_store(p, v, __ATOMIC_RELAXED, __HIP_MEMORY_SCOPE_AGENT);
}
__device__ __forceinline__ ull ald8(const ull* p){
  return __hip_atomic_load(p, __ATOMIC_RELAXED, __HIP_MEMORY_SCOPE_AGENT);
}

// ---------------- init kernels ----------------
__global__ void k_zero(float* ws){
  long long id = (long long)blockIdx.x*blockDim.x + threadIdx.x;
  long long stride = (long long)gridDim.x*blockDim.x;
  for (long long i = id; i < 196608; i += stride) ws[WS_HP1 + i] = 0.f; // hp1 + hp2
  int* bar = (int*)(ws + WS_BAR);
  for (long long i = id; i < 8192; i += stride) bar[i] = 0;
}

__global__ void k_xproj(const float* __restrict__ x, const float* __restrict__ Wih1,
                        const float* __restrict__ bih1, const float* __restrict__ bhh1,
                        float* __restrict__ ws){
  __shared__ float xs[D];
  int b = blockIdx.x;
  for (int d = threadIdx.x; d < D; d += blockDim.x) xs[d] = x[b*D + d];
  __syncthreads();
  for (int g = threadIdx.x; g < G1; g += blockDim.x){
    float acc = bih1[g] + bhh1[g];
    const float* w = &Wih1[(size_t)g*D];
    #pragma unroll 8
    for (int d = 0; d < D; ++d) acc += xs[d]*w[d];
    ws[WS_XPROJ + (size_t)b*G1 + g] = acc;
  }
}

// ---------------- per-group counter barrier (no fences) ----------------
// Ordering: every thread's atomic h-stores are drained (vmcnt) on entry to
// __syncthreads; t0's fetch_add happens after the barrier -> all stores of all
// threads in this WG are at the coherence point before the flag increments.
__device__ __forceinline__ void groupbar(int* cnt, int t, int target){
  __syncthreads();
  if (t == 0){
    asm volatile("s_waitcnt vmcnt(0)" ::: "memory");
    __hip_atomic_fetch_add(cnt, 1, __ATOMIC_RELAXED, __HIP_MEMORY_SCOPE_AGENT);
    while (__hip_atomic_load(cnt, __ATOMIC_RELAXED, __HIP_MEMORY_SCOPE_AGENT) < target){
      __builtin_amdgcn_s_sleep(2);
    }
  }
  __syncthreads();
}

// ---------------- persistent LSTM kernel ----------------
__global__ void __launch_bounds__(256, 1)
k_persist(const float* __restrict__ Whh1,
          const float* __restrict__ Wih2, const float* __restrict__ Whh2,
          const float* __restrict__ bih2, const float* __restrict__ bhh2,
          const float* __restrict__ Wout,
          float* __restrict__ ws){
  extern __shared__ float sm[];
  const int wg = blockIdx.x;
  const int t  = threadIdx.x;
  float* hp1  = ws + WS_HP1;   // [2][B][H1]
  float* hp2  = ws + WS_HP2;   // [2][B][H2]
  float* outp = ws + WS_OUTP;  // [S][NB_U][B]
  int* barbase = (int*)(ws + WS_BAR);

  if (wg < NWG_A){
    // ======= layer-1 group: units 32/WG, batch 32/WG =======
    float* wt1 = sm;               // [128 k][128 lg]
    float* ha  = sm + 16384;       // [32][132]
    float* xp  = ha + 32*132;      // [32][128]
    const int us = wg % NA_U, bs = wg / NA_U;
    const int u0 = us*32, b0 = bs*32;
    const int tx = t & 31, ty = t >> 5, bb = ty*4;
    int* cnt = barbase + bs*256;
    // stage W_hh1 slice (once), k-major; lg = lu*4 + gate
    for (int j = t; j < 128*128; j += 256){
      int k = j & 127, lg = j >> 7;
      int lu = lg >> 2, gi = lg & 3;
      wt1[k*128 + lg] = Whh1[(size_t)(gi*H1 + u0 + lu)*D + k];
    }
    // stage xproj slice (once), local-gate layout
    for (int j = t; j < 32*128; j += 256){
      int lg = j & 127, bl = j >> 7;
      int lu = lg >> 2, gi = lg & 3;
      xp[bl*128 + lg] = ws[WS_XPROJ + (size_t)(b0 + bl)*G1 + gi*H1 + u0 + lu];
    }
    float c1r[4] = {0.f,0.f,0.f,0.f};
    __syncthreads();
    for (int r = 0; r <= S; ++r){
      if (r < S){
        const int pr = (r+1)&1, pw = r&1;
        const ull* h1q = (const ull*)(hp1 + (size_t)pr*B*H1);
        for (int j = t; j < 2048; j += 256){
          int bl = j >> 6, k2 = j & 63;
          *(ull*)&ha[bl*132 + k2*2] = ald8(&h1q[(size_t)(b0+bl)*64 + k2]);
        }
        __syncthreads();
        float acc[4][4];
        #pragma unroll
        for (int i=0;i<4;++i){
          #pragma unroll
          for (int j=0;j<4;++j) acc[i][j] = xp[(bb+i)*128 + tx*4 + j];
        }
        const float4* wv = (const float4*)wt1;
        for (int k = 0; k < 128; k += 4){
          float4 w0 = wv[(k+0)*32 + tx];
          float4 w1 = wv[(k+1)*32 + tx];
          float4 w2 = wv[(k+2)*32 + tx];
          float4 w3 = wv[(k+3)*32 + tx];
          #pragma unroll
          for (int i=0;i<4;++i){
            float4 h4 = *(const float4*)&ha[(bb+i)*132 + k];
            acc[i][0] += h4.x*w0.x; acc[i][1] += h4.x*w0.y; acc[i][2] += h4.x*w0.z; acc[i][3] += h4.x*w0.w;
            acc[i][0] += h4.y*w1.x; acc[i][1] += h4.y*w1.y; acc[i][2] += h4.y*w1.z; acc[i][3] += h4.y*w1.w;
            acc[i][0] += h4.z*w2.x; acc[i][1] += h4.z*w2.y; acc[i][2] += h4.z*w2.z; acc[i][3] += h4.z*w2.w;
            acc[i][0] += h4.w*w3.x; acc[i][1] += h4.w*w3.y; acc[i][2] += h4.w*w3.z; acc[i][3] += h4.w*w3.w;
          }
        }
        #pragma unroll
        for (int i=0;i<4;++i){
          float ig = sigm(acc[i][0]);
          float fg = sigm(acc[i][1]);
          float gg = tanhx(acc[i][2]);
          float og = sigm(acc[i][3]);
          c1r[i] = fg*c1r[i] + ig*gg;
          float h = og*tanhx(c1r[i]);
          astf(&hp1[(size_t)pw*B*H1 + (size_t)(b0+bb+i)*H1 + u0 + tx], h);
        }
      }
      groupbar(cnt, t, GRP_SZ*(r+1));
    }
  } else {
    // ======= layer-2 group: units 16/WG, batch 32/WG =======
    float* wt2  = sm;              // [384 k][64 lg]
    float* hc   = sm + 384*64;     // [32][388]  (k<128: h1, k>=128: h2)
    float* bias = hc + 32*388;     // [64]
    const int wb = wg - NWG_A;
    const int us = wb % NB_U, bs = wb / NB_U;
    const int u0 = us*16, b0 = bs*32;
    const int tx = t & 15, ty = t >> 4, bb = ty*2;
    int* cnt = barbase + bs*256;
    for (int j = t; j < 64*128; j += 256){
      int k = j & 127, lg = j >> 7;
      int lu = lg >> 2, gi = lg & 3;
      wt2[k*64 + lg] = Wih2[(size_t)(gi*H2 + u0 + lu)*D + k];
    }
    for (int j = t; j < 64*256; j += 256){
      int k = j & 255, lg = j >> 8;
      int lu = lg >> 2, gi = lg & 3;
      wt2[(128+k)*64 + lg] = Whh2[(size_t)(gi*H2 + u0 + lu)*H2 + k];
    }
    if (t < 64){
      int lu = t >> 2, gi = t & 3;
      bias[t] = bih2[gi*H2 + u0 + lu] + bhh2[gi*H2 + u0 + lu];
    }
    const float wout = Wout[u0 + tx];
    float c2r[2] = {0.f, 0.f};
    __syncthreads();
    for (int r = 0; r <= S; ++r){
      if (r >= 1){
        const int tstep = r - 1;
        const int p1 = (r-1)&1;
        const int p2r = r&1, p2w = (r-1)&1;
        const ull* h1q = (const ull*)(hp1 + (size_t)p1*B*H1);
        const ull* h2q = (const ull*)(hp2 + (size_t)p2r*B*H2);
        for (int j = t; j < 2048; j += 256){
          int bl = j >> 6, k2 = j & 63;
          *(ull*)&hc[bl*388 + k2*2] = ald8(&h1q[(size_t)(b0+bl)*64 + k2]);
        }
        for (int j = t; j < 4096; j += 256){
          int bl = j >> 7, k2 = j & 127;
          *(ull*)&hc[bl*388 + 128 + k2*2] = ald8(&h2q[(size_t)(b0+bl)*128 + k2]);
        }
        __syncthreads();
        float acc[2][4];
        #pragma unroll
        for (int i=0;i<2;++i){
          #pragma unroll
          for (int j=0;j<4;++j) acc[i][j] = bias[tx*4 + j];
        }
        const float4* wv = (const float4*)wt2;
        for (int k = 0; k < 384; k += 4){
          float4 w0 = wv[(k+0)*16 + tx];
          float4 w1 = wv[(k+1)*16 + tx];
          float4 w2 = wv[(k+2)*16 + tx];
          float4 w3 = wv[(k+3)*16 + tx];
          #pragma unroll
          for (int i=0;i<2;++i){
            float4 h4 = *(const float4*)&hc[(bb+i)*388 + k];
            acc[i][0] += h4.x*w0.x; acc[i][1] += h4.x*w0.y; acc[i][2] += h4.x*w0.z; acc[i][3] += h4.x*w0.w;
            acc[i][0] += h4.y*w1.x; acc[i][1] += h4.y*w1.y; acc[i][2] += h4.y*w1.z; acc[i][3] += h4.y*w1.w;
            acc[i][0] += h4.z*w2.x; acc[i][1] += h4.z*w2.y; acc[i][2] += h4.z*w2.z; acc[i][3] += h4.z*w2.w;
            acc[i][0] += h4.w*w3.x; acc[i][1] += h4.w*w3.y; acc[i][2] += h4.w*w3.z; acc[i][3] += h4.w*w3.w;
          }
        }
        float psum[2];
        #pragma unroll
        for (int i=0;i<2;++i){
          float ig = sigm(acc[i][0]);
          float fg = sigm(acc[i][1]);
          float gg = tanhx(acc[i][2]);
          float og = sigm(acc[i][3]);
          c2r[i] = fg*c2r[i] + ig*gg;
          float h = og*tanhx(c2r[i]);
          astf(&hp2[(size_t)p2w*B*H2 + (size_t)(b0+bb+i)*H2 + u0 + tx], h);
          psum[i] = h*wout;
        }
        #pragma unroll
        for (int m = 1; m < 16; m <<= 1){
          psum[0] += __shfl_xor(psum[0], m, 64);
          psum[1] += __shfl_xor(psum[1], m, 64);
        }
        if (tx == 0){
          outp[(size_t)tstep*(NB_U*B) + us*B + (b0+bb)]     = psum[0];
          outp[(size_t)tstep*(NB_U*B) + us*B + (b0+bb+1)]   = psum[1];
        }
      }
      groupbar(cnt, t, GRP_SZ*(r+1));
    }
  }
}

// ---------------- final output assembly ----------------
__global__ void k_final(const float* __restrict__ ws, const float* __restrict__ bout,
                        float* __restrict__ out){
  int id = blockIdx.x*blockDim.x + threadIdx.x;
  if (id >= B*S) return;
  int tt = id >> 8;       // timestep
  int b  = id & 255;      // batch (consecutive lanes -> coalesced reads)
  float s = bout[0];
  const float* p = ws + WS_OUTP + (size_t)tt*(NB_U*B) + b;
  #pragma unroll
  for (int u = 0; u < NB_U; ++u) s += p[(size_t)u*B];
  out[(size_t)b*S + tt] = s;
}

extern "C" void kernel_launch(void* const* d_in, const int* in_sizes, int n_in,
                              void* d_out, int out_size, void* d_ws, size_t ws_size,
                              hipStream_t stream){
  const float* x    = (const float*)d_in[0];
  const float* Wih1 = (const float*)d_in[1];
  const float* Whh1 = (const float*)d_in[2];
  const float* bih1 = (const float*)d_in[3];
  const float* bhh1 = (const float*)d_in[4];
  const float* Wih2 = (const float*)d_in[5];
  const float* Whh2 = (const float*)d_in[6];
  const float* bih2 = (const float*)d_in[7];
  const float* bhh2 = (const float*)d_in[8];
  const float* Wout = (const float*)d_in[9];
  const float* bout = (const float*)d_in[10];
  float* ws  = (float*)d_ws;
  float* out = (float*)d_out;

  (void)hipFuncSetAttribute((const void*)k_persist,
                            hipFuncAttributeMaxDynamicSharedMemorySize, DYN_LDS);

  k_zero<<<dim3(64), dim3(256), 0, stream>>>(ws);
  k_xproj<<<dim3(B), dim3(256), 0, stream>>>(x, Wih1, bih1, bhh1, ws);
  k_persist<<<dim3(NWG), dim3(256), DYN_LDS, stream>>>(Whh1, Wih2, Whh2, bih2, bhh2, Wout, ws);
  k_final<<<dim3((B*S)/256), dim3(256), 0, stream>>>(ws, bout, out);
}

// Round 4
// 8095.403 us; speedup vs baseline: 1.3007x; 1.0342x over previous
//
#include <hip/hip_runtime.h>

#define S   512
#define B   256
#define D   128
#define H1  128
#define G1  512
#define H2  256
#define G2  1024

#define NA_U 4
#define NWG_A 32
#define NB_U 16
#define NWG_B 128
#define NWG 160
#define GRP_SZ 20               // 4 L1 + 16 L2 WGs per batch-slice group

// ws layout (float offsets)
#define WS_XPROJ 0                    // [B][G1] = 131072
#define WS_HP1   131072               // [2][B][H1] = 65536
#define WS_HP2   196608               // [2][B][H2] = 131072
#define WS_OUTP  327680               // [S][NB_U][B] = 2097152
#define WS_BAR   2424832              // int region from here (8192 ints)

#define DYN_LDS 148224                // bytes (B-group partition is the max)

typedef unsigned long long ull;

__device__ __forceinline__ float sigm(float x){ return 1.f/(1.f+__expf(-x)); }
__device__ __forceinline__ float tanhx(float x){
  x = fminf(fmaxf(x, -30.f), 30.f);
  float e = __expf(-2.f*x);
  return (1.f - e)/(1.f + e);
}

// coherent (cache-bypassing) accessors for cross-WG data
__device__ __forceinline__ void astf(float* p, float v){
  __hip_atomic_store(p, v, __ATOMIC_RELAXED, __HIP_MEMORY_SCOPE_AGENT);
}
__device__ __forceinline__ ull ald8(const ull* p){
  return __hip_atomic_load(p, __ATOMIC_RELAXED, __HIP_MEMORY_SCOPE_AGENT);
}

// ---------------- init kernels ----------------
__global__ void k_zero(float* ws){
  long long id = (long long)blockIdx.x*blockDim.x + threadIdx.x;
  long long stride = (long long)gridDim.x*blockDim.x;
  for (long long i = id; i < 196608; i += stride) ws[WS_HP1 + i] = 0.f; // hp1 + hp2
  int* bar = (int*)(ws + WS_BAR);
  for (long long i = id; i < 8192; i += stride) bar[i] = 0;
}

__global__ void k_xproj(const float* __restrict__ x, const float* __restrict__ Wih1,
                        const float* __restrict__ bih1, const float* __restrict__ bhh1,
                        float* __restrict__ ws){
  __shared__ float xs[D];
  int b = blockIdx.x;
  for (int d = threadIdx.x; d < D; d += blockDim.x) xs[d] = x[b*D + d];
  __syncthreads();
  for (int g = threadIdx.x; g < G1; g += blockDim.x){
    float acc = bih1[g] + bhh1[g];
    const float* w = &Wih1[(size_t)g*D];
    #pragma unroll 8
    for (int d = 0; d < D; ++d) acc += xs[d]*w[d];
    ws[WS_XPROJ + (size_t)b*G1 + g] = acc;
  }
}

// ---------------- single-hop flag sync ----------------
// Wait until all GRP_SZ peer flags >= need. Wave 0 polls (lanes 0..19 map to
// peers); other waves park at the barrier.
__device__ __forceinline__ void wait_group(int* gflags, int t, int need){
  if (t < 64){
    int f;
    for(;;){
      f = (t < GRP_SZ)
        ? __hip_atomic_load(&gflags[t], __ATOMIC_RELAXED, __HIP_MEMORY_SCOPE_AGENT)
        : 0x7fffffff;
      if (__all(f >= need)) break;
      __builtin_amdgcn_s_sleep(1);
    }
  }
  __syncthreads();
}

// Publish own flag = r+1 after round r. The __syncthreads() rendezvous makes
// every wave drain vmcnt (compiler emits full s_waitcnt before s_barrier), so
// all h-stores of this WG are at the coherence point before the flag store.
__device__ __forceinline__ void flag_done(int* gflags, int slot, int t, int r){
  __syncthreads();
  if (t == 0){
    __hip_atomic_store(&gflags[slot], r+1, __ATOMIC_RELAXED, __HIP_MEMORY_SCOPE_AGENT);
  }
}

// ---------------- persistent LSTM kernel ----------------
__global__ void __launch_bounds__(256, 1)
k_persist(const float* __restrict__ Whh1,
          const float* __restrict__ Wih2, const float* __restrict__ Whh2,
          const float* __restrict__ bih2, const float* __restrict__ bhh2,
          const float* __restrict__ Wout,
          float* __restrict__ ws){
  extern __shared__ float sm[];
  const int wg = blockIdx.x;
  const int t  = threadIdx.x;
  float* hp1  = ws + WS_HP1;   // [2][B][H1]
  float* hp2  = ws + WS_HP2;   // [2][B][H2]
  float* outp = ws + WS_OUTP;  // [S][NB_U][B]
  int* barbase = (int*)(ws + WS_BAR);

  if (wg < NWG_A){
    // ======= layer-1 group: units 32/WG, batch 32/WG =======
    float* wt1 = sm;               // [128 k][128 lg]
    float* ha  = sm + 16384;       // [32][132]
    float* xp  = ha + 32*132;      // [32][128]
    const int us = wg % NA_U, bs = wg / NA_U;
    const int u0 = us*32, b0 = bs*32;
    const int tx = t & 31, ty = t >> 5, bb = ty*4;
    int* gflags = barbase + bs*32;
    const int slot = us;
    // stage W_hh1 slice (once), k-major; lg = lu*4 + gate
    for (int j = t; j < 128*128; j += 256){
      int k = j & 127, lg = j >> 7;
      int lu = lg >> 2, gi = lg & 3;
      wt1[k*128 + lg] = Whh1[(size_t)(gi*H1 + u0 + lu)*D + k];
    }
    // stage xproj slice (once), local-gate layout
    for (int j = t; j < 32*128; j += 256){
      int lg = j & 127, bl = j >> 7;
      int lu = lg >> 2, gi = lg & 3;
      xp[bl*128 + lg] = ws[WS_XPROJ + (size_t)(b0 + bl)*G1 + gi*H1 + u0 + lu];
    }
    float c1r[4] = {0.f,0.f,0.f,0.f};
    __syncthreads();
    for (int r = 0; r <= S; ++r){
      if (r > 0) wait_group(gflags, t, r);
      if (r < S){
        const int pr = (r+1)&1, pw = r&1;
        const ull* h1q = (const ull*)(hp1 + (size_t)pr*B*H1);
        for (int j = t; j < 2048; j += 256){
          int bl = j >> 6, k2 = j & 63;
          *(ull*)&ha[bl*132 + k2*2] = ald8(&h1q[(size_t)(b0+bl)*64 + k2]);
        }
        __syncthreads();
        float acc[4][4];
        #pragma unroll
        for (int i=0;i<4;++i){
          #pragma unroll
          for (int j=0;j<4;++j) acc[i][j] = xp[(bb+i)*128 + tx*4 + j];
        }
        const float4* wv = (const float4*)wt1;
        for (int k = 0; k < 128; k += 4){
          float4 w0 = wv[(k+0)*32 + tx];
          float4 w1 = wv[(k+1)*32 + tx];
          float4 w2 = wv[(k+2)*32 + tx];
          float4 w3 = wv[(k+3)*32 + tx];
          #pragma unroll
          for (int i=0;i<4;++i){
            float4 h4 = *(const float4*)&ha[(bb+i)*132 + k];
            acc[i][0] += h4.x*w0.x; acc[i][1] += h4.x*w0.y; acc[i][2] += h4.x*w0.z; acc[i][3] += h4.x*w0.w;
            acc[i][0] += h4.y*w1.x; acc[i][1] += h4.y*w1.y; acc[i][2] += h4.y*w1.z; acc[i][3] += h4.y*w1.w;
            acc[i][0] += h4.z*w2.x; acc[i][1] += h4.z*w2.y; acc[i][2] += h4.z*w2.z; acc[i][3] += h4.z*w2.w;
            acc[i][0] += h4.w*w3.x; acc[i][1] += h4.w*w3.y; acc[i][2] += h4.w*w3.z; acc[i][3] += h4.w*w3.w;
          }
        }
        #pragma unroll
        for (int i=0;i<4;++i){
          float ig = sigm(acc[i][0]);
          float fg = sigm(acc[i][1]);
          float gg = tanhx(acc[i][2]);
          float og = sigm(acc[i][3]);
          c1r[i] = fg*c1r[i] + ig*gg;
          float h = og*tanhx(c1r[i]);
          astf(&hp1[(size_t)pw*B*H1 + (size_t)(b0+bb+i)*H1 + u0 + tx], h);
        }
      }
      flag_done(gflags, slot, t, r);
    }
  } else {
    // ======= layer-2 group: units 16/WG, batch 32/WG =======
    float* wt2  = sm;              // [384 k][64 lg]
    float* hc   = sm + 384*64;     // [32][388]  (k<128: h1, k>=128: h2)
    float* bias = hc + 32*388;     // [64]
    const int wb = wg - NWG_A;
    const int us = wb % NB_U, bs = wb / NB_U;
    const int u0 = us*16, b0 = bs*32;
    const int tx = t & 15, ty = t >> 4, bb = ty*2;
    int* gflags = barbase + bs*32;
    const int slot = 4 + us;
    for (int j = t; j < 64*128; j += 256){
      int k = j & 127, lg = j >> 7;
      int lu = lg >> 2, gi = lg & 3;
      wt2[k*64 + lg] = Wih2[(size_t)(gi*H2 + u0 + lu)*D + k];
    }
    for (int j = t; j < 64*256; j += 256){
      int k = j & 255, lg = j >> 8;
      int lu = lg >> 2, gi = lg & 3;
      wt2[(128+k)*64 + lg] = Whh2[(size_t)(gi*H2 + u0 + lu)*H2 + k];
    }
    if (t < 64){
      int lu = t >> 2, gi = t & 3;
      bias[t] = bih2[gi*H2 + u0 + lu] + bhh2[gi*H2 + u0 + lu];
    }
    const float wout = Wout[u0 + tx];
    float c2r[2] = {0.f, 0.f};
    __syncthreads();
    for (int r = 0; r <= S; ++r){
      if (r > 0) wait_group(gflags, t, r);
      if (r >= 1){
        const int tstep = r - 1;
        const int p1 = (r-1)&1;
        const int p2r = r&1, p2w = (r-1)&1;
        const ull* h1q = (const ull*)(hp1 + (size_t)p1*B*H1);
        const ull* h2q = (const ull*)(hp2 + (size_t)p2r*B*H2);
        for (int j = t; j < 2048; j += 256){
          int bl = j >> 6, k2 = j & 63;
          *(ull*)&hc[bl*388 + k2*2] = ald8(&h1q[(size_t)(b0+bl)*64 + k2]);
        }
        for (int j = t; j < 4096; j += 256){
          int bl = j >> 7, k2 = j & 127;
          *(ull*)&hc[bl*388 + 128 + k2*2] = ald8(&h2q[(size_t)(b0+bl)*128 + k2]);
        }
        __syncthreads();
        float acc[2][4];
        #pragma unroll
        for (int i=0;i<2;++i){
          #pragma unroll
          for (int j=0;j<4;++j) acc[i][j] = bias[tx*4 + j];
        }
        const float4* wv = (const float4*)wt2;
        for (int k = 0; k < 384; k += 4){
          float4 w0 = wv[(k+0)*16 + tx];
          float4 w1 = wv[(k+1)*16 + tx];
          float4 w2 = wv[(k+2)*16 + tx];
          float4 w3 = wv[(k+3)*16 + tx];
          #pragma unroll
          for (int i=0;i<2;++i){
            float4 h4 = *(const float4*)&hc[(bb+i)*388 + k];
            acc[i][0] += h4.x*w0.x; acc[i][1] += h4.x*w0.y; acc[i][2] += h4.x*w0.z; acc[i][3] += h4.x*w0.w;
            acc[i][0] += h4.y*w1.x; acc[i][1] += h4.y*w1.y; acc[i][2] += h4.y*w1.z; acc[i][3] += h4.y*w1.w;
            acc[i][0] += h4.z*w2.x; acc[i][1] += h4.z*w2.y; acc[i][2] += h4.z*w2.z; acc[i][3] += h4.z*w2.w;
            acc[i][0] += h4.w*w3.x; acc[i][1] += h4.w*w3.y; acc[i][2] += h4.w*w3.z; acc[i][3] += h4.w*w3.w;
          }
        }
        float psum[2];
        #pragma unroll
        for (int i=0;i<2;++i){
          float ig = sigm(acc[i][0]);
          float fg = sigm(acc[i][1]);
          float gg = tanhx(acc[i][2]);
          float og = sigm(acc[i][3]);
          c2r[i] = fg*c2r[i] + ig*gg;
          float h = og*tanhx(c2r[i]);
          astf(&hp2[(size_t)p2w*B*H2 + (size_t)(b0+bb+i)*H2 + u0 + tx], h);
          psum[i] = h*wout;
        }
        #pragma unroll
        for (int m = 1; m < 16; m <<= 1){
          psum[0] += __shfl_xor(psum[0], m, 64);
          psum[1] += __shfl_xor(psum[1], m, 64);
        }
        if (tx == 0){
          outp[(size_t)tstep*(NB_U*B) + us*B + (b0+bb)]     = psum[0];
          outp[(size_t)tstep*(NB_U*B) + us*B + (b0+bb+1)]   = psum[1];
        }
      }
      flag_done(gflags, slot, t, r);
    }
  }
}

// ---------------- final output assembly ----------------
__global__ void k_final(const float* __restrict__ ws, const float* __restrict__ bout,
                        float* __restrict__ out){
  int id = blockIdx.x*blockDim.x + threadIdx.x;
  if (id >= B*S) return;
  int tt = id >> 8;       // timestep
  int b  = id & 255;      // batch (consecutive lanes -> coalesced reads)
  float s = bout[0];
  const float* p = ws + WS_OUTP + (size_t)tt*(NB_U*B) + b;
  #pragma unroll
  for (int u = 0; u < NB_U; ++u) s += p[(size_t)u*B];
  out[(size_t)b*S + tt] = s;
}

extern "C" void kernel_launch(void* const* d_in, const int* in_sizes, int n_in,
                              void* d_out, int out_size, void* d_ws, size_t ws_size,
                              hipStream_t stream){
  const float* x    = (const float*)d_in[0];
  const float* Wih1 = (const float*)d_in[1];
  const float* Whh1 = (const float*)d_in[2];
  const float* bih1 = (const float*)d_in[3];
  const float* bhh1 = (const float*)d_in[4];
  const float* Wih2 = (const float*)d_in[5];
  const float* Whh2 = (const float*)d_in[6];
  const float* bih2 = (const float*)d_in[7];
  const float* bhh2 = (const float*)d_in[8];
  const float* Wout = (const float*)d_in[9];
  const float* bout = (const float*)d_in[10];
  float* ws  = (float*)d_ws;
  float* out = (float*)d_out;

  (void)hipFuncSetAttribute((const void*)k_persist,
                            hipFuncAttributeMaxDynamicSharedMemorySize, DYN_LDS);

  k_zero<<<dim3(64), dim3(256), 0, stream>>>(ws);
  k_xproj<<<dim3(B), dim3(256), 0, stream>>>(x, Wih1, bih1, bhh1, ws);
  k_persist<<<dim3(NWG), dim3(256), DYN_LDS, stream>>>(Whh1, Wih2, Whh2, bih2, bhh2, Wout, ws);
  k_final<<<dim3((B*S)/256), dim3(256), 0, stream>>>(ws, bout, out);
}

// Round 5
// 4571.313 us; speedup vs baseline: 2.3034x; 1.7709x over previous
//
#include <hip/hip_runtime.h>

#define S 512
#define B 256
#define D 128
#define H1 128
#define H2 256

#define NGRP 8
#define BG 32
#define WPG 10
#define NWG 80
#define GRP_FLAGS 10

// byte offsets in ws
#define OFF_XPROJ 0u
#define OFF_H1HI  524288u
#define OFF_H1LO  655360u
#define OFF_H2HI  786432u
#define OFF_H2LO  1048576u
#define OFF_OUTP  1310720u
#define OFF_FLAG  5505024u

#define DYN_LDS 67072

typedef unsigned long long ull;
typedef unsigned short ushort;
typedef __attribute__((ext_vector_type(8))) short short8;
typedef __attribute__((ext_vector_type(4))) float f32x4;

__device__ __forceinline__ ushort f2bf(float f){
  unsigned u = __float_as_uint(f);
  unsigned r = u + 0x7fffu + ((u>>16)&1u);
  return (ushort)(r>>16);
}
__device__ __forceinline__ float rcpf_(float x){ return __builtin_amdgcn_rcpf(x); }
__device__ __forceinline__ float sigm(float x){ return rcpf_(1.f + __expf(-x)); }
__device__ __forceinline__ float tanh_(float x){ return 1.f - 2.f*rcpf_(1.f + __expf(2.f*x)); }

__device__ __forceinline__ void ast8(ull* p, ull v){
  __hip_atomic_store(p, v, __ATOMIC_RELAXED, __HIP_MEMORY_SCOPE_AGENT);
}
__device__ __forceinline__ ull ald8(const ull* p){
  return __hip_atomic_load(p, __ATOMIC_RELAXED, __HIP_MEMORY_SCOPE_AGENT);
}
__device__ __forceinline__ ull pk4(ushort a, ushort b, ushort c, ushort d){
  return (ull)a | ((ull)b<<16) | ((ull)c<<32) | ((ull)d<<48);
}

__global__ void k_zero(char* wsb){
  long long id = (long long)blockIdx.x*blockDim.x + threadIdx.x;
  long long stride = (long long)gridDim.x*blockDim.x;
  ull* h = (ull*)(wsb + OFF_H1HI);
  for (long long i = id; i < 98304; i += stride) h[i] = 0ull;
  ull* f = (ull*)(wsb + OFF_FLAG);
  for (long long i = id; i < 128; i += stride) f[i] = 0ull;
}

__global__ void k_xproj(const float* __restrict__ x, const float* __restrict__ Wih1,
                        const float* __restrict__ bih1, const float* __restrict__ bhh1,
                        char* __restrict__ wsb){
  __shared__ float xs[D];
  float* xproj = (float*)(wsb + OFF_XPROJ);
  int b = blockIdx.x;
  for (int d = threadIdx.x; d < D; d += blockDim.x) xs[d] = x[b*D + d];
  __syncthreads();
  for (int g = threadIdx.x; g < 4*H1; g += blockDim.x){
    float acc = bih1[g] + bhh1[g];
    const float* w = &Wih1[(size_t)g*D];
    #pragma unroll 8
    for (int d = 0; d < D; ++d) acc += xs[d]*w[d];
    xproj[(size_t)b*512 + g] = acc;
  }
}

__device__ __forceinline__ void wait_group(int* gf, int t, int need){
  if (t < 64){
    for(;;){
      int f = (t < GRP_FLAGS)
        ? __hip_atomic_load(&gf[t], __ATOMIC_RELAXED, __HIP_MEMORY_SCOPE_AGENT)
        : 0x7fffffff;
      if (__all(f >= need)) break;
      __builtin_amdgcn_s_sleep(1);
    }
  }
  __syncthreads();
}
__device__ __forceinline__ void flag_done(int* gf, int slot, int t, int r){
  __syncthreads();
  if (t == 0){
    __hip_atomic_store(&gf[slot], r+1, __ATOMIC_RELAXED, __HIP_MEMORY_SCOPE_AGENT);
  }
}

__global__ void __launch_bounds__(256,1)
k_persist(const float* __restrict__ Whh1,
          const float* __restrict__ Wih2, const float* __restrict__ Whh2,
          const float* __restrict__ bih2, const float* __restrict__ bhh2,
          const float* __restrict__ Wout,
          char* __restrict__ wsb){
  extern __shared__ char sm[];
  const int wg = blockIdx.x;
  const int t  = threadIdx.x;
  const int grp = wg / WPG, role = wg % WPG;
  const int gb0 = grp * BG;
  const int l = t & 63, wv = t >> 6, lr = l & 15, lk = (l >> 4) * 8;

  float* xproj = (float*)(wsb + OFF_XPROJ);
  ull* h1hi = (ull*)(wsb + OFF_H1HI);
  ull* h1lo = (ull*)(wsb + OFF_H1LO);
  ull* h2hi = (ull*)(wsb + OFF_H2HI);
  ull* h2lo = (ull*)(wsb + OFF_H2LO);
  float* outp = (float*)(wsb + OFF_OUTP);
  int* gf = (int*)(wsb + OFF_FLAG) + grp*32;

  if (role < 2){
    // ================= layer-1 WG: 64 units, 32 batches =================
    const int u0 = role * 64;
    ushort* hsH = (ushort*)sm;            // [32][136] bf16
    ushort* hsL = (ushort*)(sm + 8704);   // [32][136]
    float*  gl  = (float*)(sm + 17408);   // [32][260] f32 gates

    short8 bhi[4][4], blo[4][4];
    #pragma unroll
    for (int kt=0;kt<4;++kt){
      #pragma unroll
      for (int ct=0;ct<4;++ct){
        int col = wv*64 + ct*16 + lr;
        int lu = col>>2, g = col&3;
        const float* src = Whh1 + (size_t)(g*H1 + u0 + lu)*D + kt*32 + lk;
        short8 vh, vl;
        #pragma unroll
        for (int j=0;j<8;++j){
          float w = src[j];
          ushort hb = f2bf(w);
          float hf = __uint_as_float((unsigned)hb<<16);
          vh[j] = (short)hb; vl[j] = (short)f2bf(w - hf);
        }
        bhi[kt][ct]=vh; blo[kt][ct]=vl;
      }
    }
    f32x4 xpf[2][4];
    #pragma unroll
    for (int bt=0;bt<2;++bt){
      #pragma unroll
      for (int ct=0;ct<4;++ct){
        int col = wv*64 + ct*16 + lr;
        int lu = col>>2, g = col&3;
        #pragma unroll
        for (int q=0;q<4;++q){
          int b = gb0 + bt*16 + (l>>4)*4 + q;
          xpf[bt][ct][q] = xproj[(size_t)b*512 + g*H1 + u0 + lu];
        }
      }
    }
    const int nb = t>>3, lu0 = (t&7)*8;
    float c1[8];
    #pragma unroll
    for (int j=0;j<8;++j) c1[j]=0.f;

    for (int r=0; r<=S; ++r){
      if (r>0) wait_group(gf, t, r);
      if (r<S){
        const int pr = (r+1)&1, pw = r&1;
        const ull* sH = h1hi + (size_t)pr*8192;
        const ull* sL = h1lo + (size_t)pr*8192;
        #pragma unroll
        for (int m=0;m<4;++m){
          int id = t + m*256;            // 0..1023
          int b = id>>5, k4 = id&31;
          size_t go = (size_t)(gb0+b)*32 + k4;
          *(ull*)(hsH + b*136 + k4*4) = ald8(sH+go);
          *(ull*)(hsL + b*136 + k4*4) = ald8(sL+go);
        }
        __syncthreads();
        f32x4 acc[2][4];
        #pragma unroll
        for (int bt=0;bt<2;++bt){
          #pragma unroll
          for (int ct=0;ct<4;++ct) acc[bt][ct]=xpf[bt][ct];
        }
        #pragma unroll
        for (int kt=0;kt<4;++kt){
          short8 ah[2], al[2];
          #pragma unroll
          for (int bt=0;bt<2;++bt){
            int off = (bt*16+lr)*136 + kt*32 + lk;
            ah[bt] = *(const short8*)(hsH + off);
            al[bt] = *(const short8*)(hsL + off);
          }
          #pragma unroll
          for (int bt=0;bt<2;++bt){
            #pragma unroll
            for (int ct=0;ct<4;++ct){
              acc[bt][ct] = __builtin_amdgcn_mfma_f32_16x16x32_bf16(ah[bt], bhi[kt][ct], acc[bt][ct],0,0,0);
              acc[bt][ct] = __builtin_amdgcn_mfma_f32_16x16x32_bf16(al[bt], bhi[kt][ct], acc[bt][ct],0,0,0);
              acc[bt][ct] = __builtin_amdgcn_mfma_f32_16x16x32_bf16(ah[bt], blo[kt][ct], acc[bt][ct],0,0,0);
            }
          }
        }
        #pragma unroll
        for (int bt=0;bt<2;++bt){
          #pragma unroll
          for (int ct=0;ct<4;++ct){
            #pragma unroll
            for (int q=0;q<4;++q)
              gl[(bt*16 + (l>>4)*4 + q)*260 + wv*64 + ct*16 + lr] = acc[bt][ct][q];
          }
        }
        __syncthreads();
        float hv[8];
        #pragma unroll
        for (int j=0;j<8;++j){
          f32x4 gv = *(const f32x4*)&gl[nb*260 + (lu0+j)*4];
          float ig = sigm(gv[0]), fg = sigm(gv[1]);
          float gg = tanh_(gv[2]), og = sigm(gv[3]);
          c1[j] = fg*c1[j] + ig*gg;
          hv[j] = og*tanh_(c1[j]);
        }
        ushort hb[8], lb[8];
        #pragma unroll
        for (int j=0;j<8;++j){
          hb[j] = f2bf(hv[j]);
          float hf = __uint_as_float((unsigned)hb[j]<<16);
          lb[j] = f2bf(hv[j]-hf);
        }
        size_t db = (size_t)pw*8192 + (size_t)(gb0+nb)*32 + ((u0+lu0)>>2);
        ast8(h1hi+db,   pk4(hb[0],hb[1],hb[2],hb[3]));
        ast8(h1hi+db+1, pk4(hb[4],hb[5],hb[6],hb[7]));
        ast8(h1lo+db,   pk4(lb[0],lb[1],lb[2],lb[3]));
        ast8(h1lo+db+1, pk4(lb[4],lb[5],lb[6],lb[7]));
      }
      flag_done(gf, role, t, r);
    }
  } else {
    // ================= layer-2 WG: 32 units, 32 batches =================
    const int us = role - 2;
    const int u0 = us * 32;
    ushort* hcH = (ushort*)sm;             // [32][392] bf16
    ushort* hcL = (ushort*)(sm + 25088);   // [32][392]
    float*  gl  = (float*)(sm + 50176);    // [32][132] f32 gates

    short8 bhi[12][2], blo[12][2];
    #pragma unroll
    for (int kt=0;kt<12;++kt){
      #pragma unroll
      for (int ct=0;ct<2;++ct){
        int col = wv*32 + ct*16 + lr;
        int lu = col>>2, g = col&3;
        int row = g*H2 + u0 + lu;
        const float* src = (kt<4) ? (Wih2 + (size_t)row*D + kt*32 + lk)
                                  : (Whh2 + (size_t)row*H2 + (kt-4)*32 + lk);
        short8 vh, vl;
        #pragma unroll
        for (int j=0;j<8;++j){
          float w = src[j];
          ushort hb = f2bf(w);
          float hf = __uint_as_float((unsigned)hb<<16);
          vh[j] = (short)hb; vl[j] = (short)f2bf(w - hf);
        }
        bhi[kt][ct]=vh; blo[kt][ct]=vl;
      }
    }
    float biasv[2];
    #pragma unroll
    for (int ct=0;ct<2;++ct){
      int col = wv*32 + ct*16 + lr;
      int lu = col>>2, g = col&3;
      biasv[ct] = bih2[g*H2+u0+lu] + bhh2[g*H2+u0+lu];
    }
    const int nb = t>>3, lu0 = (t&7)*4;
    float wo[4];
    #pragma unroll
    for (int j=0;j<4;++j) wo[j] = Wout[u0+lu0+j];
    float c2[4] = {0.f,0.f,0.f,0.f};

    for (int r=0; r<=S; ++r){
      if (r>0) wait_group(gf, t, r);
      if (r>=1){
        const int ts = r-1;
        const int p1 = (r-1)&1;
        const int p2r = r&1, p2w = (r-1)&1;
        const ull* s1H = h1hi + (size_t)p1*8192;
        const ull* s1L = h1lo + (size_t)p1*8192;
        const ull* s2H = h2hi + (size_t)p2r*16384;
        const ull* s2L = h2lo + (size_t)p2r*16384;
        #pragma unroll
        for (int m=0;m<12;++m){
          int id = t + m*256;          // 0..3071
          int b = id/96, r96 = id%96;
          int loff = b*392 + r96*4;
          ull vh, vl;
          if (r96 < 32){ size_t go = (size_t)(gb0+b)*32 + r96; vh = ald8(s1H+go); vl = ald8(s1L+go); }
          else         { size_t go = (size_t)(gb0+b)*64 + (r96-32); vh = ald8(s2H+go); vl = ald8(s2L+go); }
          *(ull*)(hcH + loff) = vh;
          *(ull*)(hcL + loff) = vl;
        }
        __syncthreads();
        f32x4 acc[2][2];
        #pragma unroll
        for (int bt=0;bt<2;++bt){
          #pragma unroll
          for (int ct=0;ct<2;++ct){
            f32x4 a; a[0]=biasv[ct]; a[1]=biasv[ct]; a[2]=biasv[ct]; a[3]=biasv[ct];
            acc[bt][ct]=a;
          }
        }
        #pragma unroll
        for (int kt=0;kt<12;++kt){
          short8 ah[2], al[2];
          #pragma unroll
          for (int bt=0;bt<2;++bt){
            int off = (bt*16+lr)*392 + kt*32 + lk;
            ah[bt] = *(const short8*)(hcH + off);
            al[bt] = *(const short8*)(hcL + off);
          }
          #pragma unroll
          for (int bt=0;bt<2;++bt){
            #pragma unroll
            for (int ct=0;ct<2;++ct){
              acc[bt][ct] = __builtin_amdgcn_mfma_f32_16x16x32_bf16(ah[bt], bhi[kt][ct], acc[bt][ct],0,0,0);
              acc[bt][ct] = __builtin_amdgcn_mfma_f32_16x16x32_bf16(al[bt], bhi[kt][ct], acc[bt][ct],0,0,0);
              acc[bt][ct] = __builtin_amdgcn_mfma_f32_16x16x32_bf16(ah[bt], blo[kt][ct], acc[bt][ct],0,0,0);
            }
          }
        }
        #pragma unroll
        for (int bt=0;bt<2;++bt){
          #pragma unroll
          for (int ct=0;ct<2;++ct){
            #pragma unroll
            for (int q=0;q<4;++q)
              gl[(bt*16 + (l>>4)*4 + q)*132 + wv*32 + ct*16 + lr] = acc[bt][ct][q];
          }
        }
        __syncthreads();
        float psum = 0.f;
        ushort hb[4], lb[4];
        #pragma unroll
        for (int j=0;j<4;++j){
          f32x4 gv = *(const f32x4*)&gl[nb*132 + (lu0+j)*4];
          float ig = sigm(gv[0]), fg = sigm(gv[1]);
          float gg = tanh_(gv[2]), og = sigm(gv[3]);
          c2[j] = fg*c2[j] + ig*gg;
          float h = og*tanh_(c2[j]);
          psum += h*wo[j];
          hb[j] = f2bf(h);
          lb[j] = f2bf(h - __uint_as_float((unsigned)hb[j]<<16));
        }
        size_t db = (size_t)p2w*16384 + (size_t)(gb0+nb)*64 + ((u0+lu0)>>2);
        ast8(h2hi+db, pk4(hb[0],hb[1],hb[2],hb[3]));
        ast8(h2lo+db, pk4(lb[0],lb[1],lb[2],lb[3]));
        psum += __shfl_xor(psum,1,64);
        psum += __shfl_xor(psum,2,64);
        psum += __shfl_xor(psum,4,64);
        if ((t&7)==0) outp[(size_t)ts*2048 + us*256 + gb0+nb] = psum;
      }
      flag_done(gf, role, t, r);
    }
  }
}

__global__ void k_final(const char* __restrict__ wsb, const float* __restrict__ bout,
                        float* __restrict__ out){
  const float* outp = (const float*)(wsb + OFF_OUTP);
  int id = blockIdx.x*blockDim.x + threadIdx.x;
  if (id >= B*S) return;
  int tt = id >> 8;
  int b  = id & 255;
  float s = bout[0];
  const float* p = outp + (size_t)tt*2048 + b;
  #pragma unroll
  for (int u = 0; u < 8; ++u) s += p[(size_t)u*256];
  out[(size_t)b*S + tt] = s;
}

extern "C" void kernel_launch(void* const* d_in, const int* in_sizes, int n_in,
                              void* d_out, int out_size, void* d_ws, size_t ws_size,
                              hipStream_t stream){
  const float* x    = (const float*)d_in[0];
  const float* Wih1 = (const float*)d_in[1];
  const float* Whh1 = (const float*)d_in[2];
  const float* bih1 = (const float*)d_in[3];
  const float* bhh1 = (const float*)d_in[4];
  const float* Wih2 = (const float*)d_in[5];
  const float* Whh2 = (const float*)d_in[6];
  const float* bih2 = (const float*)d_in[7];
  const float* bhh2 = (const float*)d_in[8];
  const float* Wout = (const float*)d_in[9];
  const float* bout = (const float*)d_in[10];
  char* wsb  = (char*)d_ws;
  float* out = (float*)d_out;

  (void)hipFuncSetAttribute((const void*)k_persist,
                            hipFuncAttributeMaxDynamicSharedMemorySize, DYN_LDS);

  k_zero<<<dim3(64), dim3(256), 0, stream>>>(wsb);
  k_xproj<<<dim3(B), dim3(256), 0, stream>>>(x, Wih1, bih1, bhh1, wsb);
  k_persist<<<dim3(NWG), dim3(256), DYN_LDS, stream>>>(Whh1, Wih2, Whh2, bih2, bhh2, Wout, wsb);
  k_final<<<dim3((B*S)/256), dim3(256), 0, stream>>>(wsb, bout, out);
}

// Round 6
// 2059.319 us; speedup vs baseline: 5.1131x; 2.2198x over previous
//
#include <hip/hip_runtime.h>

#define S 512
#define B 256
#define D 128
#define H1 128
#define H2 256

#define NGRP 8
#define BG 32
#define WPG 10
#define NWG 80
#define GRP_FLAGS 10

// byte offsets in ws
#define OFF_XPROJ 0u
#define OFF_H1HI  524288u
#define OFF_H1LO  655360u
#define OFF_H2HI  786432u
#define OFF_H2LO  1048576u
#define OFF_OUTP  1310720u
#define OFF_FLAG  5505024u

#define DYN_LDS 67072

typedef unsigned long long ull;
typedef unsigned short ushort;
typedef __attribute__((ext_vector_type(8))) short short8;
typedef __attribute__((ext_vector_type(4))) float f32x4;

__device__ __forceinline__ ushort f2bf(float f){
  unsigned u = __float_as_uint(f);
  unsigned r = u + 0x7fffu + ((u>>16)&1u);
  return (ushort)(r>>16);
}
__device__ __forceinline__ float rcpf_(float x){ return __builtin_amdgcn_rcpf(x); }
__device__ __forceinline__ float sigm(float x){ return rcpf_(1.f + __expf(-x)); }
__device__ __forceinline__ float tanh_(float x){ return 1.f - 2.f*rcpf_(1.f + __expf(2.f*x)); }

__device__ __forceinline__ void ast8(ull* p, ull v){
  __hip_atomic_store(p, v, __ATOMIC_RELAXED, __HIP_MEMORY_SCOPE_AGENT);
}
__device__ __forceinline__ ull ald8(const ull* p){
  return __hip_atomic_load(p, __ATOMIC_RELAXED, __HIP_MEMORY_SCOPE_AGENT);
}
__device__ __forceinline__ ull pk4(ushort a, ushort b, ushort c, ushort d){
  return (ull)a | ((ull)b<<16) | ((ull)c<<32) | ((ull)d<<48);
}

__global__ void k_zero(char* wsb){
  long long id = (long long)blockIdx.x*blockDim.x + threadIdx.x;
  long long stride = (long long)gridDim.x*blockDim.x;
  ull* h = (ull*)(wsb + OFF_H1HI);
  for (long long i = id; i < 98304; i += stride) h[i] = 0ull;
  ull* f = (ull*)(wsb + OFF_FLAG);
  for (long long i = id; i < 128; i += stride) f[i] = 0ull;
}

__global__ void k_xproj(const float* __restrict__ x, const float* __restrict__ Wih1,
                        const float* __restrict__ bih1, const float* __restrict__ bhh1,
                        char* __restrict__ wsb){
  __shared__ float xs[D];
  float* xproj = (float*)(wsb + OFF_XPROJ);
  int b = blockIdx.x;
  for (int d = threadIdx.x; d < D; d += blockDim.x) xs[d] = x[b*D + d];
  __syncthreads();
  for (int g = threadIdx.x; g < 4*H1; g += blockDim.x){
    float acc = bih1[g] + bhh1[g];
    const float* w = &Wih1[(size_t)g*D];
    #pragma unroll 8
    for (int d = 0; d < D; ++d) acc += xs[d]*w[d];
    xproj[(size_t)b*512 + g] = acc;
  }
}

__device__ __forceinline__ void wait_group(int* gf, int t, int need){
  if (t < 64){
    for(;;){
      int f = (t < GRP_FLAGS)
        ? __hip_atomic_load(&gf[t], __ATOMIC_RELAXED, __HIP_MEMORY_SCOPE_AGENT)
        : 0x7fffffff;
      if (__all(f >= need)) break;
      __builtin_amdgcn_s_sleep(1);
    }
  }
  __syncthreads();
}
__device__ __forceinline__ void flag_done(int* gf, int slot, int t, int r){
  __syncthreads();
  if (t == 0){
    __hip_atomic_store(&gf[slot], r+1, __ATOMIC_RELAXED, __HIP_MEMORY_SCOPE_AGENT);
  }
}

__global__ void __launch_bounds__(256,1)
k_persist(const float* __restrict__ Whh1,
          const float* __restrict__ Wih2, const float* __restrict__ Whh2,
          const float* __restrict__ bih2, const float* __restrict__ bhh2,
          const float* __restrict__ Wout,
          char* __restrict__ wsb){
  extern __shared__ char sm[];
  const int wg = blockIdx.x;
  const int t  = threadIdx.x;
  const int grp = wg / WPG, role = wg % WPG;
  const int gb0 = grp * BG;
  const int l = t & 63, wv = t >> 6, lr = l & 15, lk = (l >> 4) * 8;

  float* xproj = (float*)(wsb + OFF_XPROJ);
  ull* h1hi = (ull*)(wsb + OFF_H1HI);
  ull* h1lo = (ull*)(wsb + OFF_H1LO);
  ull* h2hi = (ull*)(wsb + OFF_H2HI);
  ull* h2lo = (ull*)(wsb + OFF_H2LO);
  float* outp = (float*)(wsb + OFF_OUTP);
  int* gf = (int*)(wsb + OFF_FLAG) + grp*32;

  if (role < 2){
    // ================= layer-1 WG: 64 units, 32 batches =================
    const int u0 = role * 64;
    ushort* hsH = (ushort*)sm;            // [32][136] bf16
    ushort* hsL = (ushort*)(sm + 8704);   // [32][136]
    float*  gl  = (float*)(sm + 17408);   // [32][260] f32 gates

    short8 bhi[4][4], blo[4][4];
    #pragma unroll
    for (int kt=0;kt<4;++kt){
      #pragma unroll
      for (int ct=0;ct<4;++ct){
        int col = wv*64 + ct*16 + lr;
        int lu = col>>2, g = col&3;
        const float* src = Whh1 + (size_t)(g*H1 + u0 + lu)*D + kt*32 + lk;
        short8 vh, vl;
        #pragma unroll
        for (int j=0;j<8;++j){
          float w = src[j];
          ushort hb = f2bf(w);
          float hf = __uint_as_float((unsigned)hb<<16);
          vh[j] = (short)hb; vl[j] = (short)f2bf(w - hf);
        }
        bhi[kt][ct]=vh; blo[kt][ct]=vl;
      }
    }
    f32x4 xpf[2][4];
    #pragma unroll
    for (int bt=0;bt<2;++bt){
      #pragma unroll
      for (int ct=0;ct<4;++ct){
        int col = wv*64 + ct*16 + lr;
        int lu = col>>2, g = col&3;
        #pragma unroll
        for (int q=0;q<4;++q){
          int b = gb0 + bt*16 + (l>>4)*4 + q;
          xpf[bt][ct][q] = xproj[(size_t)b*512 + g*H1 + u0 + lu];
        }
      }
    }
    const int nb = t>>3, lu0 = (t&7)*8;
    float c1[8];
    #pragma unroll
    for (int j=0;j<8;++j) c1[j]=0.f;

    for (int r=0; r<=S; ++r){
      if (r>0) wait_group(gf, t, r);
      if (r<S){
        const int pr = (r+1)&1, pw = r&1;
        const ull* sH = h1hi + (size_t)pr*8192;
        const ull* sL = h1lo + (size_t)pr*8192;
        // --- phase 1: issue ALL coherent loads into registers (pipelined) ---
        ull tH[4], tL[4];
        #pragma unroll
        for (int m=0;m<4;++m){
          int id = t + m*256;            // 0..1023
          int b = id>>5, k4 = id&31;
          size_t go = (size_t)(gb0+b)*32 + k4;
          tH[m] = ald8(sH+go);
          tL[m] = ald8(sL+go);
        }
        // --- phase 2: LDS writes ---
        #pragma unroll
        for (int m=0;m<4;++m){
          int id = t + m*256;
          int b = id>>5, k4 = id&31;
          *(ull*)(hsH + b*136 + k4*4) = tH[m];
          *(ull*)(hsL + b*136 + k4*4) = tL[m];
        }
        __syncthreads();
        f32x4 acc[2][4];
        #pragma unroll
        for (int bt=0;bt<2;++bt){
          #pragma unroll
          for (int ct=0;ct<4;++ct) acc[bt][ct]=xpf[bt][ct];
        }
        #pragma unroll
        for (int kt=0;kt<4;++kt){
          short8 ah[2], al[2];
          #pragma unroll
          for (int bt=0;bt<2;++bt){
            int off = (bt*16+lr)*136 + kt*32 + lk;
            ah[bt] = *(const short8*)(hsH + off);
            al[bt] = *(const short8*)(hsL + off);
          }
          #pragma unroll
          for (int bt=0;bt<2;++bt){
            #pragma unroll
            for (int ct=0;ct<4;++ct){
              acc[bt][ct] = __builtin_amdgcn_mfma_f32_16x16x32_bf16(ah[bt], bhi[kt][ct], acc[bt][ct],0,0,0);
              acc[bt][ct] = __builtin_amdgcn_mfma_f32_16x16x32_bf16(al[bt], bhi[kt][ct], acc[bt][ct],0,0,0);
              acc[bt][ct] = __builtin_amdgcn_mfma_f32_16x16x32_bf16(ah[bt], blo[kt][ct], acc[bt][ct],0,0,0);
            }
          }
        }
        #pragma unroll
        for (int bt=0;bt<2;++bt){
          #pragma unroll
          for (int ct=0;ct<4;++ct){
            #pragma unroll
            for (int q=0;q<4;++q)
              gl[(bt*16 + (l>>4)*4 + q)*260 + wv*64 + ct*16 + lr] = acc[bt][ct][q];
          }
        }
        __syncthreads();
        float hv[8];
        #pragma unroll
        for (int j=0;j<8;++j){
          f32x4 gv = *(const f32x4*)&gl[nb*260 + (lu0+j)*4];
          float ig = sigm(gv[0]), fg = sigm(gv[1]);
          float gg = tanh_(gv[2]), og = sigm(gv[3]);
          c1[j] = fg*c1[j] + ig*gg;
          hv[j] = og*tanh_(c1[j]);
        }
        ushort hb[8], lb[8];
        #pragma unroll
        for (int j=0;j<8;++j){
          hb[j] = f2bf(hv[j]);
          float hf = __uint_as_float((unsigned)hb[j]<<16);
          lb[j] = f2bf(hv[j]-hf);
        }
        size_t db = (size_t)pw*8192 + (size_t)(gb0+nb)*32 + ((u0+lu0)>>2);
        ast8(h1hi+db,   pk4(hb[0],hb[1],hb[2],hb[3]));
        ast8(h1hi+db+1, pk4(hb[4],hb[5],hb[6],hb[7]));
        ast8(h1lo+db,   pk4(lb[0],lb[1],lb[2],lb[3]));
        ast8(h1lo+db+1, pk4(lb[4],lb[5],lb[6],lb[7]));
      }
      flag_done(gf, role, t, r);
    }
  } else {
    // ================= layer-2 WG: 32 units, 32 batches =================
    const int us = role - 2;
    const int u0 = us * 32;
    ushort* hcH = (ushort*)sm;             // [32][392] bf16
    ushort* hcL = (ushort*)(sm + 25088);   // [32][392]
    float*  gl  = (float*)(sm + 50176);    // [32][132] f32 gates

    short8 bhi[12][2], blo[12][2];
    #pragma unroll
    for (int kt=0;kt<12;++kt){
      #pragma unroll
      for (int ct=0;ct<2;++ct){
        int col = wv*32 + ct*16 + lr;
        int lu = col>>2, g = col&3;
        int row = g*H2 + u0 + lu;
        const float* src = (kt<4) ? (Wih2 + (size_t)row*D + kt*32 + lk)
                                  : (Whh2 + (size_t)row*H2 + (kt-4)*32 + lk);
        short8 vh, vl;
        #pragma unroll
        for (int j=0;j<8;++j){
          float w = src[j];
          ushort hb = f2bf(w);
          float hf = __uint_as_float((unsigned)hb<<16);
          vh[j] = (short)hb; vl[j] = (short)f2bf(w - hf);
        }
        bhi[kt][ct]=vh; blo[kt][ct]=vl;
      }
    }
    float biasv[2];
    #pragma unroll
    for (int ct=0;ct<2;++ct){
      int col = wv*32 + ct*16 + lr;
      int lu = col>>2, g = col&3;
      biasv[ct] = bih2[g*H2+u0+lu] + bhh2[g*H2+u0+lu];
    }
    const int nb = t>>3, lu0 = (t&7)*4;
    float wo[4];
    #pragma unroll
    for (int j=0;j<4;++j) wo[j] = Wout[u0+lu0+j];
    float c2[4] = {0.f,0.f,0.f,0.f};

    for (int r=0; r<=S; ++r){
      if (r>0) wait_group(gf, t, r);
      if (r>=1){
        const int ts = r-1;
        const int p1 = (r-1)&1;
        const int p2r = r&1, p2w = (r-1)&1;
        const ull* s1H = h1hi + (size_t)p1*8192;
        const ull* s1L = h1lo + (size_t)p1*8192;
        const ull* s2H = h2hi + (size_t)p2r*16384;
        const ull* s2L = h2lo + (size_t)p2r*16384;
        // --- phase 1: issue ALL coherent loads into registers (pipelined,
        //     no divergent branch around the loads) ---
        ull t1H[4], t1L[4], t2H[8], t2L[8];
        #pragma unroll
        for (int m=0;m<4;++m){
          int id = t + m*256;            // 0..1023 -> h1 (32 ull rows)
          int b = id>>5, s = id&31;
          size_t go = (size_t)(gb0+b)*32 + s;
          t1H[m] = ald8(s1H+go);
          t1L[m] = ald8(s1L+go);
        }
        #pragma unroll
        for (int m=0;m<8;++m){
          int id = t + m*256;            // 0..2047 -> h2 (64 ull rows)
          int b = id>>6, s = id&63;
          size_t go = (size_t)(gb0+b)*64 + s;
          t2H[m] = ald8(s2H+go);
          t2L[m] = ald8(s2L+go);
        }
        // --- phase 2: LDS writes ---
        #pragma unroll
        for (int m=0;m<4;++m){
          int id = t + m*256;
          int b = id>>5, s = id&31;
          *(ull*)(hcH + b*392 + s*4) = t1H[m];
          *(ull*)(hcL + b*392 + s*4) = t1L[m];
        }
        #pragma unroll
        for (int m=0;m<8;++m){
          int id = t + m*256;
          int b = id>>6, s = id&63;
          *(ull*)(hcH + b*392 + 128 + s*4) = t2H[m];
          *(ull*)(hcL + b*392 + 128 + s*4) = t2L[m];
        }
        __syncthreads();
        f32x4 acc[2][2];
        #pragma unroll
        for (int bt=0;bt<2;++bt){
          #pragma unroll
          for (int ct=0;ct<2;++ct){
            f32x4 a; a[0]=biasv[ct]; a[1]=biasv[ct]; a[2]=biasv[ct]; a[3]=biasv[ct];
            acc[bt][ct]=a;
          }
        }
        #pragma unroll
        for (int kt=0;kt<12;++kt){
          short8 ah[2], al[2];
          #pragma unroll
          for (int bt=0;bt<2;++bt){
            int off = (bt*16+lr)*392 + kt*32 + lk;
            ah[bt] = *(const short8*)(hcH + off);
            al[bt] = *(const short8*)(hcL + off);
          }
          #pragma unroll
          for (int bt=0;bt<2;++bt){
            #pragma unroll
            for (int ct=0;ct<2;++ct){
              acc[bt][ct] = __builtin_amdgcn_mfma_f32_16x16x32_bf16(ah[bt], bhi[kt][ct], acc[bt][ct],0,0,0);
              acc[bt][ct] = __builtin_amdgcn_mfma_f32_16x16x32_bf16(al[bt], bhi[kt][ct], acc[bt][ct],0,0,0);
              acc[bt][ct] = __builtin_amdgcn_mfma_f32_16x16x32_bf16(ah[bt], blo[kt][ct], acc[bt][ct],0,0,0);
            }
          }
        }
        #pragma unroll
        for (int bt=0;bt<2;++bt){
          #pragma unroll
          for (int ct=0;ct<2;++ct){
            #pragma unroll
            for (int q=0;q<4;++q)
              gl[(bt*16 + (l>>4)*4 + q)*132 + wv*32 + ct*16 + lr] = acc[bt][ct][q];
          }
        }
        __syncthreads();
        float psum = 0.f;
        ushort hb[4], lb[4];
        #pragma unroll
        for (int j=0;j<4;++j){
          f32x4 gv = *(const f32x4*)&gl[nb*132 + (lu0+j)*4];
          float ig = sigm(gv[0]), fg = sigm(gv[1]);
          float gg = tanh_(gv[2]), og = sigm(gv[3]);
          c2[j] = fg*c2[j] + ig*gg;
          float h = og*tanh_(c2[j]);
          psum += h*wo[j];
          hb[j] = f2bf(h);
          lb[j] = f2bf(h - __uint_as_float((unsigned)hb[j]<<16));
        }
        size_t db = (size_t)p2w*16384 + (size_t)(gb0+nb)*64 + ((u0+lu0)>>2);
        ast8(h2hi+db, pk4(hb[0],hb[1],hb[2],hb[3]));
        ast8(h2lo+db, pk4(lb[0],lb[1],lb[2],lb[3]));
        psum += __shfl_xor(psum,1,64);
        psum += __shfl_xor(psum,2,64);
        psum += __shfl_xor(psum,4,64);
        if ((t&7)==0) outp[(size_t)ts*2048 + us*256 + gb0+nb] = psum;
      }
      flag_done(gf, role, t, r);
    }
  }
}

__global__ void k_final(const char* __restrict__ wsb, const float* __restrict__ bout,
                        float* __restrict__ out){
  const float* outp = (const float*)(wsb + OFF_OUTP);
  int id = blockIdx.x*blockDim.x + threadIdx.x;
  if (id >= B*S) return;
  int tt = id >> 8;
  int b  = id & 255;
  float s = bout[0];
  const float* p = outp + (size_t)tt*2048 + b;
  #pragma unroll
  for (int u = 0; u < 8; ++u) s += p[(size_t)u*256];
  out[(size_t)b*S + tt] = s;
}

extern "C" void kernel_launch(void* const* d_in, const int* in_sizes, int n_in,
                              void* d_out, int out_size, void* d_ws, size_t ws_size,
                              hipStream_t stream){
  const float* x    = (const float*)d_in[0];
  const float* Wih1 = (const float*)d_in[1];
  const float* Whh1 = (const float*)d_in[2];
  const float* bih1 = (const float*)d_in[3];
  const float* bhh1 = (const float*)d_in[4];
  const float* Wih2 = (const float*)d_in[5];
  const float* Whh2 = (const float*)d_in[6];
  const float* bih2 = (const float*)d_in[7];
  const float* bhh2 = (const float*)d_in[8];
  const float* Wout = (const float*)d_in[9];
  const float* bout = (const float*)d_in[10];
  char* wsb  = (char*)d_ws;
  float* out = (float*)d_out;

  (void)hipFuncSetAttribute((const void*)k_persist,
                            hipFuncAttributeMaxDynamicSharedMemorySize, DYN_LDS);

  k_zero<<<dim3(64), dim3(256), 0, stream>>>(wsb);
  k_xproj<<<dim3(B), dim3(256), 0, stream>>>(x, Wih1, bih1, bhh1, wsb);
  k_persist<<<dim3(NWG), dim3(256), DYN_LDS, stream>>>(Whh1, Wih2, Whh2, bih2, bhh2, Wout, wsb);
  k_final<<<dim3((B*S)/256), dim3(256), 0, stream>>>(wsb, bout, out);
}